// Round 7
// baseline (109.876 us; speedup 1.0000x reference)
//
#include <hip/hip_runtime.h>
#include <math.h>

#define NN 4096
#define NFEAT 1870
#define KB 1920          // padded K for W1T planes
#define KSPLIT 4
#define KCHUNK 480
#define NSTEP 15         // KCHUNK / 32
#define HID 256
#define EMB 16
#define MAXDEG 128

typedef __attribute__((ext_vector_type(8))) _Float16 f16x8;
typedef __attribute__((ext_vector_type(4))) float f32x4;

__device__ __forceinline__ ushort f2h(float f) {
    _Float16 h = (_Float16)f;
    return __builtin_bit_cast(ushort, h);
}

struct af32 { float2 v[4]; };

__device__ __forceinline__ af32 load_a_raw(const float* __restrict__ rp, int k0) {
    af32 r;
    if (k0 + 8 <= NFEAT) {
#pragma unroll
        for (int j = 0; j < 4; ++j) r.v[j] = *(const float2*)&rp[k0 + j * 2];
    } else {
#pragma unroll
        for (int j = 0; j < 4; ++j) {
            float a = (k0 + j * 2     < NFEAT) ? rp[k0 + j * 2]     : 0.f;
            float b = (k0 + j * 2 + 1 < NFEAT) ? rp[k0 + j * 2 + 1] : 0.f;
            r.v[j] = make_float2(a, b);
        }
    }
    return r;
}
__device__ __forceinline__ f16x8 cvt_a(af32 r) {
    f16x8 o;
#pragma unroll
    for (int j = 0; j < 4; ++j) {
        o[j * 2]     = (_Float16)r.v[j].x;
        o[j * 2 + 1] = (_Float16)r.v[j].y;
    }
    return o;
}

// ---------------------------------------------------------------------------
// Fused prep. Blocks [0,NN): sparse extract via block-wide parallel scan
// (one block per row, thread owns 16 adj elems). Blocks [NN,NN+120): W1T f16.
// ---------------------------------------------------------------------------
__global__ __launch_bounds__(256) void prep_kernel(
    const float* __restrict__ W1, ushort* __restrict__ Wh,
    const float* __restrict__ adj, const float* __restrict__ Mmat,
    int* __restrict__ nnz, int* __restrict__ gidx, float* __restrict__ Mg)
{
    const int b = blockIdx.x;
    const int tid = threadIdx.x;
    if (b < NN) {
        const int row = b;
        const int lane = tid & 63, wv = tid >> 6;
        const float* arow = adj + (size_t)row * NN + tid * 16;
        float4 v[4];
#pragma unroll
        for (int i = 0; i < 4; ++i) v[i] = *(const float4*)&arow[i * 4];
        unsigned mask = 0;
#pragma unroll
        for (int i = 0; i < 4; ++i) {
            if (v[i].x > 0.f) mask |= 1u << (i * 4 + 0);
            if (v[i].y > 0.f) mask |= 1u << (i * 4 + 1);
            if (v[i].z > 0.f) mask |= 1u << (i * 4 + 2);
            if (v[i].w > 0.f) mask |= 1u << (i * 4 + 3);
        }
        const int cnt = __popc(mask);
        int incl = cnt;
#pragma unroll
        for (int off = 1; off < 64; off <<= 1) {
            int y = __shfl_up(incl, off, 64);
            if (lane >= off) incl += y;
        }
        __shared__ int wsums[4];
        if (lane == 63) wsums[wv] = incl;
        __syncthreads();
        int base = incl - cnt;
#pragma unroll
        for (int i = 0; i < 4; ++i)
            if (i < wv) base += wsums[i];
        if (tid == 0) {
            int total = wsums[0] + wsums[1] + wsums[2] + wsums[3];
            nnz[row] = min(total, MAXDEG);
        }
        unsigned mm = mask;
        int off = base;
        while (mm) {
            int bit = __ffs(mm) - 1;
            mm &= mm - 1;
            if (off < MAXDEG) {
                int j = tid * 16 + bit;
                gidx[(size_t)row * MAXDEG + off] = j;
                Mg[(size_t)row * MAXDEG + off] = Mmat[(size_t)row * NN + j];
            }
            ++off;
        }
    } else {
        // ---- W1 [NFEAT][HID] -> W1T f16 [HID][KB], zero-padded K ----
        __shared__ float t[64][65];
        const int bb = b - NN;
        const int k0 = (bb % 30) * 64, n0 = (bb / 30) * 64;
        const int kk = tid >> 2, c4 = (tid & 3) * 16;
#pragma unroll
        for (int j = 0; j < 4; ++j) {
            int k = k0 + kk;
            float4 v = make_float4(0.f, 0.f, 0.f, 0.f);
            if (k < NFEAT) v = *(const float4*)&W1[(size_t)k * HID + n0 + c4 + j * 4];
            t[kk][c4 + j * 4 + 0] = v.x; t[kk][c4 + j * 4 + 1] = v.y;
            t[kk][c4 + j * 4 + 2] = v.z; t[kk][c4 + j * 4 + 3] = v.w;
        }
        __syncthreads();
        const int on = tid >> 2, ok4 = (tid & 3) * 16;
#pragma unroll
        for (int j = 0; j < 4; ++j) {
            ushort hh[4];
#pragma unroll
            for (int i = 0; i < 4; ++i)
                hh[i] = f2h(t[ok4 + j * 4 + i][on]);
            size_t o = (size_t)(n0 + on) * KB + k0 + ok4 + j * 4;
            *(ushort4*)&Wh[o] = *(ushort4*)hh;
        }
    }
}

// ---------------------------------------------------------------------------
// h1 partials = x(fp32, converted in-reg) @ W1T^T. LDS-free, barrier-free.
// Wave = 16x64 tile; block = 4 waves = 16 rows x 256 cols. Grid = 256*4.
// Register double-buffered A(raw fp32)/B prefetch across 15 K-steps.
// ---------------------------------------------------------------------------
__global__ __launch_bounds__(256, 4) void gemm_xw1(
    const float* __restrict__ Xg,    // [NN][NFEAT]
    const ushort* __restrict__ Bg,   // [HID][KB]
    float* __restrict__ Cpart)       // [KSPLIT][NN][HID]
{
    const int tid = threadIdx.x;
    const int lane = tid & 63;
    const int cgrp = tid >> 6;
    const int mgrp = blockIdx.x >> 2;
    const int z    = blockIdx.x & 3;
    const int row0 = mgrp * 16;
    const int col0 = cgrp * 64;
    const int kbeg = z * KCHUNK;
    const int fr = lane & 15, fs = lane >> 4;

    const float* Arow = Xg + (size_t)(row0 + fr) * NFEAT;
    const ushort* Bbase = Bg + (size_t)(col0 + fr) * KB + kbeg + fs * 8;

    af32 araw = load_a_raw(Arow, kbeg + fs * 8);
    f16x8 bc[4];
#pragma unroll
    for (int n = 0; n < 4; ++n)
        bc[n] = *(const f16x8*)&Bbase[(size_t)n * 16 * KB];

    f32x4 acc[4] = {};
#pragma unroll
    for (int sk = 0; sk < NSTEP; ++sk) {
        f16x8 ac = cvt_a(araw);
        af32 anxt;
        f16x8 bn[4];
        if (sk + 1 < NSTEP) {
            anxt = load_a_raw(Arow, kbeg + (sk + 1) * 32 + fs * 8);
#pragma unroll
            for (int n = 0; n < 4; ++n)
                bn[n] = *(const f16x8*)&Bbase[(size_t)n * 16 * KB + (sk + 1) * 32];
        }
#pragma unroll
        for (int n = 0; n < 4; ++n)
            acc[n] = __builtin_amdgcn_mfma_f32_16x16x32_f16(ac, bc[n], acc[n], 0, 0, 0);
        if (sk + 1 < NSTEP) {
            araw = anxt;
#pragma unroll
            for (int n = 0; n < 4; ++n) bc[n] = bn[n];
        }
    }
    float* Cp = Cpart + (size_t)z * NN * HID;
#pragma unroll
    for (int n = 0; n < 4; ++n)
#pragma unroll
        for (int r = 0; r < 4; ++r) {
            int row = row0 + fs * 4 + r;
            int col = col0 + n * 16 + fr;
            Cp[(size_t)row * HID + col] = acc[n][r];
        }
}

// ---------------------------------------------------------------------------
// h1 = sum of 4 split-K partials; fused fs1/fn1 (one wave per row).
// ---------------------------------------------------------------------------
__global__ __launch_bounds__(256) void reduce_h1f_kernel(
    const float* __restrict__ part, float* __restrict__ h1,
    const float* __restrict__ a_s, const float* __restrict__ a_n,
    float* __restrict__ fs, float* __restrict__ fn)
{
    const int tid = threadIdx.x, wv = tid >> 6, lane = tid & 63;
    const int row = blockIdx.x * 4 + wv;
    const int d0 = lane * 4;
    const size_t o = (size_t)row * HID + d0;
    float4 s = *(const float4*)&part[o];
#pragma unroll
    for (int ch = 1; ch < KSPLIT; ++ch) {
        float4 p = *(const float4*)&part[(size_t)ch * NN * HID + o];
        s.x += p.x; s.y += p.y; s.z += p.z; s.w += p.w;
    }
    *(float4*)&h1[o] = s;
    float4 as4 = *(const float4*)&a_s[d0];
    float4 an4 = *(const float4*)&a_n[d0];
    float ps = s.x * as4.x + s.y * as4.y + s.z * as4.z + s.w * as4.w;
    float pn = s.x * an4.x + s.y * an4.y + s.z * an4.z + s.w * an4.w;
#pragma unroll
    for (int off = 32; off > 0; off >>= 1) {
        ps += __shfl_down(ps, off, 64);
        pn += __shfl_down(pn, off, 64);
    }
    if (lane == 0) { fs[row] = ps; fn[row] = pn; }
}

// ---------------------------------------------------------------------------
// Layer-1 fused sparse softmax + SpMM: g1[row,:] = elu( softmax_nb @ h1 ).
// ---------------------------------------------------------------------------
__global__ __launch_bounds__(256) void spmm1_kernel(
    const int* __restrict__ nnz, const int* __restrict__ gidx,
    const float* __restrict__ Mg,
    const float* __restrict__ fs, const float* __restrict__ fn,
    const float* __restrict__ h1, float* __restrict__ g1)
{
    __shared__ float p_s[MAXDEG];
    __shared__ int j_s[MAXDEG];
    __shared__ float wred[4], wsum[4];
    const int row = blockIdx.x;
    const int tid = threadIdx.x;
    const int lane = tid & 63, wv = tid >> 6;
    const int cnt = nnz[row];
    const float fsi = fs[row];

    float lmax = -3.0e38f;
    for (int s = tid; s < cnt; s += 256) {
        int j = gidx[(size_t)row * MAXDEG + s];
        j_s[s] = j;
        float e = (fsi + fn[j]) * Mg[(size_t)row * MAXDEG + s];
        e = (e > 0.f) ? e : 0.2f * e;
        p_s[s] = e;
        lmax = fmaxf(lmax, e);
    }
#pragma unroll
    for (int off = 32; off > 0; off >>= 1)
        lmax = fmaxf(lmax, __shfl_down(lmax, off, 64));
    if (lane == 0) wred[wv] = lmax;
    __syncthreads();
    const float m = fmaxf(fmaxf(wred[0], wred[1]), fmaxf(wred[2], wred[3]));

    float lsum = 0.f;
    for (int s = tid; s < cnt; s += 256) {
        float p = __expf(p_s[s] - m);
        p_s[s] = p;
        lsum += p;
    }
#pragma unroll
    for (int off = 32; off > 0; off >>= 1)
        lsum += __shfl_down(lsum, off, 64);
    if (lane == 0) wsum[wv] = lsum;
    __syncthreads();
    const float inv = 1.f / (wsum[0] + wsum[1] + wsum[2] + wsum[3]);

    float acc = 0.f;
#pragma unroll 4
    for (int s = 0; s < cnt; ++s)
        acc += p_s[s] * h1[(size_t)j_s[s] * HID + tid];
    float v = acc * inv;
    v = (v > 0.f) ? v : (__expf(v) - 1.f);
    g1[(size_t)row * HID + tid] = v;
}

// ---------------------------------------------------------------------------
// h2 = g1 @ W2 with fused fs2/fn2 epilogue.
// ---------------------------------------------------------------------------
__global__ __launch_bounds__(256) void gemm_h2_kernel(
    const float* __restrict__ g1, const float* __restrict__ W2,
    const float* __restrict__ a_s2, const float* __restrict__ a_n2,
    float* __restrict__ h2, float* __restrict__ fs2, float* __restrict__ fn2)
{
    __shared__ float Ws[256][16];
    __shared__ float Gs[16][257];
    const int tid = threadIdx.x;
    const int row0 = blockIdx.x * 16;
#pragma unroll
    for (int i = 0; i < 16; ++i) {
        int idx = tid + i * 256;
        Ws[idx >> 4][idx & 15] = W2[idx];
    }
#pragma unroll
    for (int i = 0; i < 16; ++i) {
        int idx = tid + i * 256;
        Gs[idx >> 8][idx & 255] = g1[(size_t)(row0 + (idx >> 8)) * HID + (idx & 255)];
    }
    __syncthreads();
    const int r = tid >> 4, c = tid & 15;
    float acc = 0.f;
#pragma unroll 8
    for (int k = 0; k < 256; ++k)
        acc += Gs[r][k] * Ws[k][c];
    h2[(size_t)(row0 + r) * EMB + c] = acc;

    float ps = acc * a_s2[c];
    float pn = acc * a_n2[c];
#pragma unroll
    for (int off = 1; off < 16; off <<= 1) {
        ps += __shfl_xor(ps, off, 64);
        pn += __shfl_xor(pn, off, 64);
    }
    if (c == 0) { fs2[row0 + r] = ps; fn2[row0 + r] = pn; }
}

// ---------------------------------------------------------------------------
// Layer-2 fused sparse softmax + PV + ELU + L2-normalize -> z. 1 wave/row.
// ---------------------------------------------------------------------------
__global__ __launch_bounds__(256) void spmm2_kernel(
    const int* __restrict__ nnz, const int* __restrict__ gidx,
    const float* __restrict__ Mg,
    const float* __restrict__ fs, const float* __restrict__ fn,
    const float* __restrict__ h2, float* __restrict__ z)
{
    __shared__ float p_s[4][MAXDEG];
    __shared__ int j_s[4][MAXDEG];
    const int tid = threadIdx.x;
    const int wv = tid >> 6, lane = tid & 63;
    const int row = blockIdx.x * 4 + wv;
    const int cnt = nnz[row];
    const float fsi = fs[row];

    float lmax = -3.0e38f;
    for (int s = lane; s < cnt; s += 64) {
        int j = gidx[(size_t)row * MAXDEG + s];
        j_s[wv][s] = j;
        float e = (fsi + fn[j]) * Mg[(size_t)row * MAXDEG + s];
        e = (e > 0.f) ? e : 0.2f * e;
        p_s[wv][s] = e;
        lmax = fmaxf(lmax, e);
    }
#pragma unroll
    for (int off = 1; off < 64; off <<= 1)
        lmax = fmaxf(lmax, __shfl_xor(lmax, off, 64));

    float lsum = 0.f;
    for (int s = lane; s < cnt; s += 64) {
        float p = __expf(p_s[wv][s] - lmax);
        p_s[wv][s] = p;
        lsum += p;
    }
#pragma unroll
    for (int off = 1; off < 64; off <<= 1)
        lsum += __shfl_xor(lsum, off, 64);
    const float inv = 1.f / lsum;

    const int s0 = lane >> 4, d = lane & 15;
    float acc = 0.f;
    for (int s = s0; s < cnt; s += 4)
        acc += p_s[wv][s] * h2[(size_t)j_s[wv][s] * EMB + d];
    acc += __shfl_xor(acc, 16, 64);
    acc += __shfl_xor(acc, 32, 64);

    float v = acc * inv;
    v = (v > 0.f) ? v : (__expf(v) - 1.f);
    float ss = v * v;
#pragma unroll
    for (int off = 1; off < 16; off <<= 1)
        ss += __shfl_xor(ss, off, 64);
    float zn = v / fmaxf(sqrtf(ss), 1e-12f);
    if (lane < 16) z[(size_t)row * EMB + lane] = zn;
}

// ---------------------------------------------------------------------------
// A_pred = sigmoid(z @ z^T).  64x64 tile per block.
// ---------------------------------------------------------------------------
__global__ __launch_bounds__(256) void apred_kernel(
    const float* __restrict__ z, float* __restrict__ out)
{
    __shared__ float zr[64][20];
    __shared__ float zc[64][20];
    const int tid = threadIdx.x;
    const int r0 = blockIdx.y * 64, c0 = blockIdx.x * 64;
#pragma unroll
    for (int i = 0; i < 4; ++i) {
        int idx = tid + i * 256;
        int rr = idx >> 4, d = idx & 15;
        zr[rr][d] = z[(size_t)(r0 + rr) * EMB + d];
        zc[rr][d] = z[(size_t)(c0 + rr) * EMB + d];
    }
    __syncthreads();
    const int tx = tid & 15, ty = tid >> 4;
    float rb[4][16], cb[4][16];
#pragma unroll
    for (int i = 0; i < 4; ++i)
#pragma unroll
        for (int d = 0; d < 16; ++d) {
            rb[i][d] = zr[ty * 4 + i][d];
            cb[i][d] = zc[tx * 4 + i][d];
        }
#pragma unroll
    for (int i = 0; i < 4; ++i) {
        float4 o;
        float v[4];
#pragma unroll
        for (int j = 0; j < 4; ++j) {
            float s = 0.f;
#pragma unroll
            for (int d = 0; d < 16; ++d) s += rb[i][d] * cb[j][d];
            v[j] = 1.f / (1.f + __expf(-s));
        }
        o.x = v[0]; o.y = v[1]; o.z = v[2]; o.w = v[3];
        *reinterpret_cast<float4*>(
            &out[(size_t)(r0 + ty * 4 + i) * NN + c0 + tx * 4]) = o;
    }
}

// ---------------------------------------------------------------------------
extern "C" void kernel_launch(void* const* d_in, const int* in_sizes, int n_in,
                              void* d_out, int out_size, void* d_ws, size_t ws_size,
                              hipStream_t stream)
{
    const float* x    = (const float*)d_in[0];
    const float* adj  = (const float*)d_in[1];
    const float* Mm   = (const float*)d_in[2];
    const float* W1   = (const float*)d_in[3];
    const float* a_s1 = (const float*)d_in[4];
    const float* a_n1 = (const float*)d_in[5];
    const float* W2   = (const float*)d_in[6];
    const float* a_s2 = (const float*)d_in[7];
    const float* a_n2 = (const float*)d_in[8];

    float* out = (float*)d_out;
    float* z   = out + (size_t)NN * NN;
    // split-K partials live in the (dead until apred) A_pred region: 16.8 MB
    float* part = out;

    char* w = (char*)d_ws;
    float* h1    = (float*)w;  w += (size_t)NN * HID * 4;       // 4 MB
    float* g1    = (float*)w;  w += (size_t)NN * HID * 4;       // 4 MB
    ushort* W1Th = (ushort*)w; w += (size_t)HID * KB * 2;       // 1 MB
    float* h2    = (float*)w;  w += (size_t)NN * EMB * 4;
    int*   nnzp  = (int*)w;    w += NN * 4;
    int*   gidx  = (int*)w;    w += (size_t)NN * MAXDEG * 4;    // 2 MB
    float* Mg    = (float*)w;  w += (size_t)NN * MAXDEG * 4;    // 2 MB
    float* fs1   = (float*)w;  w += NN * 4;
    float* fn1   = (float*)w;  w += NN * 4;
    float* fs2   = (float*)w;  w += NN * 4;
    float* fn2   = (float*)w;  w += NN * 4;

    // ---- fused prep: sparsity extraction (parallel scan) | W1T->f16 ----
    prep_kernel<<<NN + 120, 256, 0, stream>>>(W1, W1Th, adj, Mm, nnzp, gidx, Mg);

    // ---- layer 1 ----
    gemm_xw1<<<(NN / 16) * KSPLIT, 256, 0, stream>>>(x, W1Th, part);
    reduce_h1f_kernel<<<NN / 4, 256, 0, stream>>>(part, h1, a_s1, a_n1, fs1, fn1);
    spmm1_kernel<<<NN, 256, 0, stream>>>(nnzp, gidx, Mg, fs1, fn1, h1, g1);

    // ---- layer 2 ----
    gemm_h2_kernel<<<256, 256, 0, stream>>>(g1, W2, a_s2, a_n2, h2, fs2, fn2);
    spmm2_kernel<<<NN / 4, 256, 0, stream>>>(nnzp, gidx, Mg, fs2, fn2, h2, z);

    // ---- epilogue ----
    apred_kernel<<<dim3(64, 64), 256, 0, stream>>>(z, out);
}

// Round 8
// 95.091 us; speedup vs baseline: 1.1555x; 1.1555x over previous
//
#include <hip/hip_runtime.h>
#include <math.h>

#define NN 4096
#define NFEAT 1870
#define KB2 2048         // padded K for f16 planes (zero-padded past NFEAT)
#define KSPLIT 8
#define KCHUNK 256       // KB2 / KSPLIT
#define BK 32
#define HID 256
#define EMB 16
#define MAXDEG 128

typedef __attribute__((ext_vector_type(8))) _Float16 f16x8;
typedef __attribute__((ext_vector_type(4))) float f32x4;

__device__ __forceinline__ ushort f2h(float f) {
    _Float16 h = (_Float16)f;
    return __builtin_bit_cast(ushort, h);
}

__device__ __forceinline__ void gload_lds16(const void* g, void* l) {
    __builtin_amdgcn_global_load_lds(
        (const __attribute__((address_space(1))) unsigned int*)g,
        (__attribute__((address_space(3))) unsigned int*)l, 16, 0, 0);
}

// ---------------------------------------------------------------------------
// Fused prep.
//   blocks [0,NN):        sparse extract via block-wide parallel scan
//   blocks [NN,2NN):      x row -> f16 [NN][KB2] zero-padded
//   blocks [2NN,2NN+128): W1 -> W1T f16 [HID][KB2] zero-padded
// ---------------------------------------------------------------------------
__global__ __launch_bounds__(256) void prep_kernel(
    const float* __restrict__ x, ushort* __restrict__ xf,
    const float* __restrict__ W1, ushort* __restrict__ Wh,
    const float* __restrict__ adj, const float* __restrict__ Mmat,
    int* __restrict__ nnz, int* __restrict__ gidx, float* __restrict__ Mg)
{
    const int b = blockIdx.x;
    const int tid = threadIdx.x;
    if (b < NN) {
        // ---- sparse extract, one block per row, thread owns 16 adj elems ----
        const int row = b;
        const int lane = tid & 63, wv = tid >> 6;
        const float* arow = adj + (size_t)row * NN + tid * 16;
        float4 v[4];
#pragma unroll
        for (int i = 0; i < 4; ++i) v[i] = *(const float4*)&arow[i * 4];
        unsigned mask = 0;
#pragma unroll
        for (int i = 0; i < 4; ++i) {
            if (v[i].x > 0.f) mask |= 1u << (i * 4 + 0);
            if (v[i].y > 0.f) mask |= 1u << (i * 4 + 1);
            if (v[i].z > 0.f) mask |= 1u << (i * 4 + 2);
            if (v[i].w > 0.f) mask |= 1u << (i * 4 + 3);
        }
        const int cnt = __popc(mask);
        int incl = cnt;
#pragma unroll
        for (int off = 1; off < 64; off <<= 1) {
            int y = __shfl_up(incl, off, 64);
            if (lane >= off) incl += y;
        }
        __shared__ int wsums[4];
        if (lane == 63) wsums[wv] = incl;
        __syncthreads();
        int base = incl - cnt;
#pragma unroll
        for (int i = 0; i < 4; ++i)
            if (i < wv) base += wsums[i];
        if (tid == 0) {
            int total = wsums[0] + wsums[1] + wsums[2] + wsums[3];
            nnz[row] = min(total, MAXDEG);
        }
        unsigned mm = mask;
        int off = base;
        while (mm) {
            int bit = __ffs(mm) - 1;
            mm &= mm - 1;
            if (off < MAXDEG) {
                int j = tid * 16 + bit;
                gidx[(size_t)row * MAXDEG + off] = j;
                Mg[(size_t)row * MAXDEG + off] = Mmat[(size_t)row * NN + j];
            }
            ++off;
        }
    } else if (b < 2 * NN) {
        // ---- x row -> f16, zero-pad to KB2 ----
        const int row = b - NN;
        const int c0 = tid * 8;
        float v[8];
        if (c0 + 8 <= NFEAT) {
#pragma unroll
            for (int j = 0; j < 4; ++j) {
                float2 t = *(const float2*)&x[(size_t)row * NFEAT + c0 + j * 2];
                v[j * 2] = t.x; v[j * 2 + 1] = t.y;
            }
        } else {
#pragma unroll
            for (int j = 0; j < 8; ++j)
                v[j] = (c0 + j < NFEAT) ? x[(size_t)row * NFEAT + c0 + j] : 0.f;
        }
        ushort u[8];
#pragma unroll
        for (int j = 0; j < 8; ++j) u[j] = f2h(v[j]);
        *(int4*)&xf[(size_t)row * KB2 + c0] = *(int4*)u;
    } else {
        // ---- W1 [NFEAT][HID] -> W1T f16 [HID][KB2], zero-padded ----
        __shared__ float t[64][65];
        const int bb = b - 2 * NN;
        const int k0 = (bb & 31) * 64, n0 = (bb >> 5) * 64;
        const int kk = tid >> 2, c4 = (tid & 3) * 16;
#pragma unroll
        for (int j = 0; j < 4; ++j) {
            int k = k0 + kk;
            float4 v = make_float4(0.f, 0.f, 0.f, 0.f);
            if (k < NFEAT) v = *(const float4*)&W1[(size_t)k * HID + n0 + c4 + j * 4];
            t[kk][c4 + j * 4 + 0] = v.x; t[kk][c4 + j * 4 + 1] = v.y;
            t[kk][c4 + j * 4 + 2] = v.z; t[kk][c4 + j * 4 + 3] = v.w;
        }
        __syncthreads();
        const int on = tid >> 2, ok4 = (tid & 3) * 16;
#pragma unroll
        for (int j = 0; j < 4; ++j) {
            ushort hh[4];
#pragma unroll
            for (int i = 0; i < 4; ++i)
                hh[i] = f2h(t[ok4 + j * 4 + i][on]);
            size_t o = (size_t)(n0 + on) * KB2 + k0 + ok4 + j * 4;
            *(ushort4*)&Wh[o] = *(ushort4*)hh;
        }
    }
}

// ---------------------------------------------------------------------------
// h1 partials = xf16 @ W1T^T.  m97 structure: 128x128 tile, 4 waves (2x2),
// BK=32, global_load_lds width-16 staging (linear LDS dest, inverse-XOR-
// swizzled global source, XOR-swizzled ds_read), split-K x8.
// ---------------------------------------------------------------------------
__global__ __launch_bounds__(256, 2) void gemm_xw1(
    const ushort* __restrict__ Ag,   // [NN][KB2] f16
    const ushort* __restrict__ Bg,   // [HID][KB2] f16
    float* __restrict__ Cpart)       // [KSPLIT][NN][HID]
{
    __shared__ ushort Ah[128 * BK];
    __shared__ ushort Bh[128 * BK];
    const int tid = threadIdx.x;
    const int lane = tid & 63;
    const int w = tid >> 6;
    const int wr = w >> 1, wc = w & 1;
    const int row0 = blockIdx.x * 128;
    const int col0 = blockIdx.y * 128;
    const int kbeg = blockIdx.z * KCHUNK;
    const int fr = lane & 15, fs = lane >> 4;

    f32x4 acc[4][4] = {};

    for (int ks = 0; ks < KCHUNK / BK; ++ks) {
        const int k0 = kbeg + ks * BK;
        __syncthreads();
#pragma unroll
        for (int i = 0; i < 2; ++i) {
            int idx = i * 256 + tid;
            int r = idx >> 2, t = idx & 3;
            int kslot = (t ^ (r & 3)) * 8;
            gload_lds16(&Ag[(size_t)(row0 + r) * KB2 + k0 + kslot], &Ah[idx * 8]);
            gload_lds16(&Bg[(size_t)(col0 + r) * KB2 + k0 + kslot], &Bh[idx * 8]);
        }
        __syncthreads();
        f16x8 af[4], bf[4];
#pragma unroll
        for (int m = 0; m < 4; ++m) {
            int r = wr * 64 + m * 16 + fr;
            af[m] = *(const f16x8*)&Ah[r * BK + ((fs ^ (r & 3)) * 8)];
        }
#pragma unroll
        for (int n = 0; n < 4; ++n) {
            int r = wc * 64 + n * 16 + fr;
            bf[n] = *(const f16x8*)&Bh[r * BK + ((fs ^ (r & 3)) * 8)];
        }
#pragma unroll
        for (int m = 0; m < 4; ++m)
#pragma unroll
            for (int n = 0; n < 4; ++n)
                acc[m][n] = __builtin_amdgcn_mfma_f32_16x16x32_f16(
                    af[m], bf[n], acc[m][n], 0, 0, 0);
    }
    float* Cp = Cpart + (size_t)blockIdx.z * NN * HID;
#pragma unroll
    for (int m = 0; m < 4; ++m)
#pragma unroll
        for (int n = 0; n < 4; ++n)
#pragma unroll
            for (int r = 0; r < 4; ++r) {
                int row = row0 + wr * 64 + m * 16 + fs * 4 + r;
                int col = col0 + wc * 64 + n * 16 + fr;
                Cp[(size_t)row * HID + col] = acc[m][n][r];
            }
}

// ---------------------------------------------------------------------------
// h1 = sum of 8 split-K partials; fused fs1/fn1 (one wave per row).
// ---------------------------------------------------------------------------
__global__ __launch_bounds__(256) void reduce_h1f_kernel(
    const float* __restrict__ part, float* __restrict__ h1,
    const float* __restrict__ a_s, const float* __restrict__ a_n,
    float* __restrict__ fs, float* __restrict__ fn)
{
    const int tid = threadIdx.x, wv = tid >> 6, lane = tid & 63;
    const int row = blockIdx.x * 4 + wv;
    const int d0 = lane * 4;
    const size_t o = (size_t)row * HID + d0;
    float4 s = *(const float4*)&part[o];
#pragma unroll
    for (int ch = 1; ch < KSPLIT; ++ch) {
        float4 p = *(const float4*)&part[(size_t)ch * NN * HID + o];
        s.x += p.x; s.y += p.y; s.z += p.z; s.w += p.w;
    }
    *(float4*)&h1[o] = s;
    float4 as4 = *(const float4*)&a_s[d0];
    float4 an4 = *(const float4*)&a_n[d0];
    float ps = s.x * as4.x + s.y * as4.y + s.z * as4.z + s.w * as4.w;
    float pn = s.x * an4.x + s.y * an4.y + s.z * an4.z + s.w * an4.w;
#pragma unroll
    for (int off = 32; off > 0; off >>= 1) {
        ps += __shfl_down(ps, off, 64);
        pn += __shfl_down(pn, off, 64);
    }
    if (lane == 0) { fs[row] = ps; fn[row] = pn; }
}

// ---------------------------------------------------------------------------
// Layer-1 fused sparse softmax + SpMM: g1[row,:] = elu( softmax_nb @ h1 ).
// ---------------------------------------------------------------------------
__global__ __launch_bounds__(256) void spmm1_kernel(
    const int* __restrict__ nnz, const int* __restrict__ gidx,
    const float* __restrict__ Mg,
    const float* __restrict__ fs, const float* __restrict__ fn,
    const float* __restrict__ h1, float* __restrict__ g1)
{
    __shared__ float p_s[MAXDEG];
    __shared__ int j_s[MAXDEG];
    __shared__ float wred[4], wsum[4];
    const int row = blockIdx.x;
    const int tid = threadIdx.x;
    const int lane = tid & 63, wv = tid >> 6;
    const int cnt = nnz[row];
    const float fsi = fs[row];

    float lmax = -3.0e38f;
    for (int s = tid; s < cnt; s += 256) {
        int j = gidx[(size_t)row * MAXDEG + s];
        j_s[s] = j;
        float e = (fsi + fn[j]) * Mg[(size_t)row * MAXDEG + s];
        e = (e > 0.f) ? e : 0.2f * e;
        p_s[s] = e;
        lmax = fmaxf(lmax, e);
    }
#pragma unroll
    for (int off = 32; off > 0; off >>= 1)
        lmax = fmaxf(lmax, __shfl_down(lmax, off, 64));
    if (lane == 0) wred[wv] = lmax;
    __syncthreads();
    const float m = fmaxf(fmaxf(wred[0], wred[1]), fmaxf(wred[2], wred[3]));

    float lsum = 0.f;
    for (int s = tid; s < cnt; s += 256) {
        float p = __expf(p_s[s] - m);
        p_s[s] = p;
        lsum += p;
    }
#pragma unroll
    for (int off = 32; off > 0; off >>= 1)
        lsum += __shfl_down(lsum, off, 64);
    if (lane == 0) wsum[wv] = lsum;
    __syncthreads();
    const float inv = 1.f / (wsum[0] + wsum[1] + wsum[2] + wsum[3]);

    float acc = 0.f;
#pragma unroll 4
    for (int s = 0; s < cnt; ++s)
        acc += p_s[s] * h1[(size_t)j_s[s] * HID + tid];
    float v = acc * inv;
    v = (v > 0.f) ? v : (__expf(v) - 1.f);
    g1[(size_t)row * HID + tid] = v;
}

// ---------------------------------------------------------------------------
// h2 = g1 @ W2 with fused fs2/fn2 epilogue.
// ---------------------------------------------------------------------------
__global__ __launch_bounds__(256) void gemm_h2_kernel(
    const float* __restrict__ g1, const float* __restrict__ W2,
    const float* __restrict__ a_s2, const float* __restrict__ a_n2,
    float* __restrict__ h2, float* __restrict__ fs2, float* __restrict__ fn2)
{
    __shared__ float Ws[256][16];
    __shared__ float Gs[16][257];
    const int tid = threadIdx.x;
    const int row0 = blockIdx.x * 16;
#pragma unroll
    for (int i = 0; i < 16; ++i) {
        int idx = tid + i * 256;
        Ws[idx >> 4][idx & 15] = W2[idx];
    }
#pragma unroll
    for (int i = 0; i < 16; ++i) {
        int idx = tid + i * 256;
        Gs[idx >> 8][idx & 255] = g1[(size_t)(row0 + (idx >> 8)) * HID + (idx & 255)];
    }
    __syncthreads();
    const int r = tid >> 4, c = tid & 15;
    float acc = 0.f;
#pragma unroll 8
    for (int k = 0; k < 256; ++k)
        acc += Gs[r][k] * Ws[k][c];
    h2[(size_t)(row0 + r) * EMB + c] = acc;

    float ps = acc * a_s2[c];
    float pn = acc * a_n2[c];
#pragma unroll
    for (int off = 1; off < 16; off <<= 1) {
        ps += __shfl_xor(ps, off, 64);
        pn += __shfl_xor(pn, off, 64);
    }
    if (c == 0) { fs2[row0 + r] = ps; fn2[row0 + r] = pn; }
}

// ---------------------------------------------------------------------------
// Layer-2 fused sparse softmax + PV + ELU + L2-normalize -> z. 1 wave/row.
// ---------------------------------------------------------------------------
__global__ __launch_bounds__(256) void spmm2_kernel(
    const int* __restrict__ nnz, const int* __restrict__ gidx,
    const float* __restrict__ Mg,
    const float* __restrict__ fs, const float* __restrict__ fn,
    const float* __restrict__ h2, float* __restrict__ z)
{
    __shared__ float p_s[4][MAXDEG];
    __shared__ int j_s[4][MAXDEG];
    const int tid = threadIdx.x;
    const int wv = tid >> 6, lane = tid & 63;
    const int row = blockIdx.x * 4 + wv;
    const int cnt = nnz[row];
    const float fsi = fs[row];

    float lmax = -3.0e38f;
    for (int s = lane; s < cnt; s += 64) {
        int j = gidx[(size_t)row * MAXDEG + s];
        j_s[wv][s] = j;
        float e = (fsi + fn[j]) * Mg[(size_t)row * MAXDEG + s];
        e = (e > 0.f) ? e : 0.2f * e;
        p_s[wv][s] = e;
        lmax = fmaxf(lmax, e);
    }
#pragma unroll
    for (int off = 1; off < 64; off <<= 1)
        lmax = fmaxf(lmax, __shfl_xor(lmax, off, 64));

    float lsum = 0.f;
    for (int s = lane; s < cnt; s += 64) {
        float p = __expf(p_s[wv][s] - lmax);
        p_s[wv][s] = p;
        lsum += p;
    }
#pragma unroll
    for (int off = 1; off < 64; off <<= 1)
        lsum += __shfl_xor(lsum, off, 64);
    const float inv = 1.f / lsum;

    const int s0 = lane >> 4, d = lane & 15;
    float acc = 0.f;
    for (int s = s0; s < cnt; s += 4)
        acc += p_s[wv][s] * h2[(size_t)j_s[wv][s] * EMB + d];
    acc += __shfl_xor(acc, 16, 64);
    acc += __shfl_xor(acc, 32, 64);

    float v = acc * inv;
    v = (v > 0.f) ? v : (__expf(v) - 1.f);
    float ss = v * v;
#pragma unroll
    for (int off = 1; off < 16; off <<= 1)
        ss += __shfl_xor(ss, off, 64);
    float zn = v / fmaxf(sqrtf(ss), 1e-12f);
    if (lane < 16) z[(size_t)row * EMB + lane] = zn;
}

// ---------------------------------------------------------------------------
// A_pred = sigmoid(z @ z^T).  64x64 tile per block.
// ---------------------------------------------------------------------------
__global__ __launch_bounds__(256) void apred_kernel(
    const float* __restrict__ z, float* __restrict__ out)
{
    __shared__ float zr[64][20];
    __shared__ float zc[64][20];
    const int tid = threadIdx.x;
    const int r0 = blockIdx.y * 64, c0 = blockIdx.x * 64;
#pragma unroll
    for (int i = 0; i < 4; ++i) {
        int idx = tid + i * 256;
        int rr = idx >> 4, d = idx & 15;
        zr[rr][d] = z[(size_t)(r0 + rr) * EMB + d];
        zc[rr][d] = z[(size_t)(c0 + rr) * EMB + d];
    }
    __syncthreads();
    const int tx = tid & 15, ty = tid >> 4;
    float rb[4][16], cb[4][16];
#pragma unroll
    for (int i = 0; i < 4; ++i)
#pragma unroll
        for (int d = 0; d < 16; ++d) {
            rb[i][d] = zr[ty * 4 + i][d];
            cb[i][d] = zc[tx * 4 + i][d];
        }
#pragma unroll
    for (int i = 0; i < 4; ++i) {
        float4 o;
        float v[4];
#pragma unroll
        for (int j = 0; j < 4; ++j) {
            float s = 0.f;
#pragma unroll
            for (int d = 0; d < 16; ++d) s += rb[i][d] * cb[j][d];
            v[j] = 1.f / (1.f + __expf(-s));
        }
        o.x = v[0]; o.y = v[1]; o.z = v[2]; o.w = v[3];
        *reinterpret_cast<float4*>(
            &out[(size_t)(r0 + ty * 4 + i) * NN + c0 + tx * 4]) = o;
    }
}

// ---------------------------------------------------------------------------
extern "C" void kernel_launch(void* const* d_in, const int* in_sizes, int n_in,
                              void* d_out, int out_size, void* d_ws, size_t ws_size,
                              hipStream_t stream)
{
    const float* x    = (const float*)d_in[0];
    const float* adj  = (const float*)d_in[1];
    const float* Mm   = (const float*)d_in[2];
    const float* W1   = (const float*)d_in[3];
    const float* a_s1 = (const float*)d_in[4];
    const float* a_n1 = (const float*)d_in[5];
    const float* W2   = (const float*)d_in[6];
    const float* a_s2 = (const float*)d_in[7];
    const float* a_n2 = (const float*)d_in[8];

    float* out = (float*)d_out;
    float* z   = out + (size_t)NN * NN;
    // split-K partials live in the (dead until apred) A_pred region: 33.6 MB
    float* part = out;

    char* w = (char*)d_ws;
    float* h1    = (float*)w;  w += (size_t)NN * HID * 4;       // 4 MB
    float* g1    = (float*)w;  w += (size_t)NN * HID * 4;       // 4 MB
    ushort* xf16 = (ushort*)w; w += (size_t)NN * KB2 * 2;       // 16.8 MB
    ushort* W1Th = (ushort*)w; w += (size_t)HID * KB2 * 2;      // 1 MB
    float* h2    = (float*)w;  w += (size_t)NN * EMB * 4;
    int*   nnzp  = (int*)w;    w += NN * 4;
    int*   gidx  = (int*)w;    w += (size_t)NN * MAXDEG * 4;    // 2 MB
    float* Mg    = (float*)w;  w += (size_t)NN * MAXDEG * 4;    // 2 MB
    float* fs1   = (float*)w;  w += NN * 4;
    float* fn1   = (float*)w;  w += NN * 4;
    float* fs2   = (float*)w;  w += NN * 4;
    float* fn2   = (float*)w;  w += NN * 4;

    // ---- fused prep: extract (parallel scan) | x->f16 | W1T->f16 ----
    prep_kernel<<<2 * NN + 128, 256, 0, stream>>>(
        x, xf16, W1, W1Th, adj, Mm, nnzp, gidx, Mg);

    // ---- layer 1 ----
    gemm_xw1<<<dim3(32, 2, KSPLIT), 256, 0, stream>>>(xf16, W1Th, part);
    reduce_h1f_kernel<<<NN / 4, 256, 0, stream>>>(part, h1, a_s1, a_n1, fs1, fn1);
    spmm1_kernel<<<NN, 256, 0, stream>>>(nnzp, gidx, Mg, fs1, fn1, h1, g1);

    // ---- layer 2 ----
    gemm_h2_kernel<<<256, 256, 0, stream>>>(g1, W2, a_s2, a_n2, h2, fs2, fn2);
    spmm2_kernel<<<NN / 4, 256, 0, stream>>>(nnzp, gidx, Mg, fs2, fn2, h2, z);

    // ---- epilogue ----
    apred_kernel<<<dim3(64, 64), 256, 0, stream>>>(z, out);
}